// Round 15
// baseline (131.218 us; speedup 1.0000x reference)
//
#include <hip/hip_runtime.h>
#include <hip/hip_bf16.h>

#define BB 4
#define CC 128
#define NN 4096
#define NHEAD 4
#define HDIM 32
#define KSPLIT 2
// Session lessons:
// r2/r10/r12: KSPLIT=4 "explosions" were REGISTER SPILLS from
//   __launch_bounds__(256,8) (VGPR 56->32); never strangle the allocator.
// r13: occupancy is a null lever (8 waves/SIMD, dur unchanged).
// r11: XCD swizzle cuts FETCH 3.3x but attn isn't BW-bound; total +3us.
// r6: W fragments must come from LDS inside the MFMA loop.
// r7: qkv@512thr raced replay verification — 256 thr only.
// r9: staging-VALU micro-opts are a dead end.
// r15 (this): attn pipes sum instead of overlap (measured 45us ~= MFMA 15.5
//   + trans ~14-27 + LDS 17 summed; occupancy null) -> PHASE-LOCK theory:
//   barrier-cadenced waves all burst the same pipe simultaneously. Fix =
//   intra-wave 2-tile software pipeline (QK[i+1] independent of REST[i]),
//   4-buffer LDS ring, 1 barrier/tile (same count), launch_bounds(256,3).

typedef short bf16x8_t __attribute__((ext_vector_type(8)));  // 8 bf16 (4 VGPRs)
typedef float f32x4_t __attribute__((ext_vector_type(4)));
typedef int i32x4_t __attribute__((ext_vector_type(4)));

#define MFMA16(a, b, c) __builtin_amdgcn_mfma_f32_16x16x32_bf16(a, b, c, 0, 0, 0)
#define EXP2(x) __builtin_amdgcn_exp2f(x)

// scores use exp2: fold log2(e) into q scale (softmax invariant)
#define QSCALE (0.17677669529663687f * 1.4426950408889634f)

// RNE float->bf16 (finite inputs only)
static __device__ inline unsigned short f2bf(float f) {
  unsigned u = __builtin_bit_cast(unsigned, f);
  u += 0x7fffu + ((u >> 16) & 1u);
  return (unsigned short)(u >> 16);
}
static __device__ inline unsigned pk2(float lo, float hi) {  // RNE pack pair
  return (unsigned)f2bf(lo) | ((unsigned)f2bf(hi) << 16);
}
// pack two f32 -> bf16 pair by TRUNCATION: single v_perm_b32
static __device__ inline unsigned pack_trunc(float lo, float hi) {
  return __builtin_amdgcn_perm(__builtin_bit_cast(unsigned, hi),
                               __builtin_bit_cast(unsigned, lo), 0x07060302u);
}

// async global->LDS, 16 B per lane. gsrc is PER-LANE (gather); LDS dest =
// uniform base + lane*16.
static __device__ inline void gload_lds16(const unsigned short* gsrc, void* ldst) {
  __builtin_amdgcn_global_load_lds(
      (const __attribute__((address_space(1))) unsigned int*)gsrc,
      (__attribute__((address_space(3))) unsigned int*)ldst, 16, 0, 0);
}

// ---------------------------------------------------------------------------
// QKV projection via MFMA — unchanged from r8/r14 (best verified).
// 256 thr, 4 waves, grid (64, B, 3). x-tile staged first, W fp32->bf16 into
// wsb (packed uint2 stores). vt (proj==2) aliases xsb. LDS ~52.2KB.
// ---------------------------------------------------------------------------
__global__ __launch_bounds__(256) void qkv_mfma_kernel(
    const float* __restrict__ x,
    const float* __restrict__ wq, const float* __restrict__ wk,
    const float* __restrict__ wv,
    const float* __restrict__ bq, const float* __restrict__ bk,
    const float* __restrict__ bv,
    unsigned short* __restrict__ qt, unsigned short* __restrict__ kt,
    unsigned short* __restrict__ vg) {
  __shared__ __attribute__((aligned(16))) unsigned short wsb[128][136];  // 34.8KB
  __shared__ __attribute__((aligned(16))) unsigned short xsb[64][136];   // 17.4KB
  unsigned short(*vt)[66] = (unsigned short(*)[66]) & xsb[0][0];  // alias (16.9KB)

  const int b = blockIdx.y, nt = blockIdx.x, proj = blockIdx.z;
  const int tid = threadIdx.x;

  const float* wsrc = (proj == 0) ? wq : (proj == 1) ? wk : wv;
  const float wscale = (proj == 0) ? QSCALE : 1.0f;

  // stage x-tile first (HBM): [n][c] bf16 transpose
#pragma unroll
  for (int i = 0; i < 8; i++) {
    int f = tid + 256 * i;  // 2048 float4 slots
    int c = f >> 4, n4 = (f & 15) * 4;
    float4 v4 = *(const float4*)(x + ((size_t)b * CC + c) * NN + nt * 64 + n4);
    xsb[n4 + 0][c] = f2bf(v4.x);
    xsb[n4 + 1][c] = f2bf(v4.y);
    xsb[n4 + 2][c] = f2bf(v4.z);
    xsb[n4 + 3][c] = f2bf(v4.w);
  }

  // stage W: 4096 float4 over 256 thr, coalesced reads, packed b64 LDS writes
#pragma unroll
  for (int i = 0; i < 16; i++) {
    int idx = i * 256 + tid;           // float4 index
    int o = idx >> 5, c4 = (idx & 31) * 4;
    float4 v4 = *(const float4*)(wsrc + (size_t)o * CC + c4);
    uint2 p;
    p.x = pk2(v4.x * wscale, v4.y * wscale);
    p.y = pk2(v4.z * wscale, v4.w * wscale);
    *(uint2*)&wsb[o][c4] = p;  // 8B aligned
  }
  __syncthreads();

  const int lane = tid & 63, w = tid >> 6;
  const int l16 = lane & 15, g = lane >> 4;
  const int nl = w * 16;
  const int ngl = nt * 64 + nl;

  bf16x8_t xf[4];
#pragma unroll
  for (int ks = 0; ks < 4; ks++)
    xf[ks] = *(const bf16x8_t*)&xsb[nl + l16][ks * 32 + g * 8];
  __syncthreads();  // xsb dead; vt (alias) may now be written

  const float* bias = (proj == 0) ? bq : (proj == 1) ? bk : bv;
  const float bsc = (proj == 0) ? QSCALE : 1.0f;
  unsigned short* qkdst = proj ? kt : qt;

#pragma unroll
  for (int ot = 0; ot < 8; ot++) {
    f32x4_t acc;
#pragma unroll
    for (int r = 0; r < 4; r++) acc[r] = bias[ot * 16 + g * 4 + r] * bsc;
#pragma unroll
    for (int ks = 0; ks < 4; ks++) {
      bf16x8_t wf = *(const bf16x8_t*)&wsb[ot * 16 + l16][ks * 32 + g * 8];
      acc = MFMA16(wf, xf[ks], acc);
    }
    if (proj < 2) {
      // lane holds d = (ot&15 base) consecutive 4; pair with g^1 for 8
      unsigned p0 = pk2(acc[0], acc[1]);
      unsigned p1 = pk2(acc[2], acc[3]);
      unsigned q0 = (unsigned)__shfl_xor((int)p0, 16);
      unsigned q1 = (unsigned)__shfl_xor((int)p1, 16);
      if ((g & 1) == 0) {
        int hh = ot >> 1, dblk = (ot & 1) * 2 + (g >> 1);
        unsigned short* dst =
            qkdst + (((size_t)(b * NHEAD + hh) * 4 + dblk) * NN + ngl + l16) * 8;
        uint4 val = make_uint4(p0, p1, q0, q1);
        *(uint4*)dst = val;
      }
    } else {
#pragma unroll
      for (int r = 0; r < 4; r++) vt[ot * 16 + g * 4 + r][nl + l16] = f2bf(acc[r]);
    }
  }

  if (proj == 2) {
    __syncthreads();
    // emit vg: 1024 16B chunks, perfectly sequential stores
#pragma unroll
    for (int c = 0; c < 4; c++) {
      int cid = c * 256 + tid;
      int hh = cid >> 8, inner = cid & 255;
      int g2 = inner & 3, l16v = (inner >> 2) & 15, fh = inner >> 6;
      int fv = fh >> 1, half = fh & 1;
      int o = hh * 32 + half * 16 + l16v;
      int n0 = fv * 32 + g2 * 4;
      unsigned d0 = *(const unsigned*)&vt[o][n0];
      unsigned d1 = *(const unsigned*)&vt[o][n0 + 2];
      unsigned d2 = *(const unsigned*)&vt[o][n0 + 16];
      unsigned d3 = *(const unsigned*)&vt[o][n0 + 18];
      uint4 val = make_uint4(d0, d1, d2, d3);
      *(uint4*)(vg + (((size_t)(b * NHEAD + hh) * 64 + nt) * 256 + inner) * 8) = val;
    }
  }
}

// ---------------------------------------------------------------------------
// Flash attention — r15: intra-wave 2-tile software pipeline.
// 4-buffer LDS ring (32KB); per tile t: staged at iter t-2, QK'd at t-1,
// REST'd (exp/pack/PV, V from LDS) at t. One barrier per tile (same count
// as r8). QK(t+1) is register-independent of REST(t) -> scheduler can
// interleave v_mfma with v_exp across tiles, breaking the phase-lock.
// Hazards: stage writes buf[(t+2)&3]; concurrent QK reads (t+1)&3, REST
// reads t&3 — disjoint; each buffer's rewrite is >=2 barriers after its
// last read. launch_bounds(256,3): ~168 VGPR budget, no spill (r12 lesson);
// expected live ~130-140 VGPR -> 3 waves/SIMD (occupancy proven non-binding).
// ---------------------------------------------------------------------------
__global__ __launch_bounds__(256, 3) void attn_mfma5_kernel(
    const unsigned short* __restrict__ qt, const unsigned short* __restrict__ kt,
    const unsigned short* __restrict__ vg,
    unsigned* __restrict__ opart, float* __restrict__ lpart) {
  __shared__ __attribute__((aligned(16))) unsigned short smem[4][4096];  // ring: K 2048, V 2048 each

  const int chunk = blockIdx.x & (KSPLIT - 1), nt = blockIdx.x / KSPLIT;
  const int h = blockIdx.y, b = blockIdx.z;
  const int bh = b * NHEAD + h;
  const int tid = threadIdx.x, lane = tid & 63, wid = tid >> 6;
  const int l16 = lane & 15, g = lane >> 4;
  const int nbase = nt * 128 + wid * 32;

  const unsigned short* qb = qt + (size_t)bh * NN * HDIM;  // [dblk][n][8]
  const unsigned short* kb = kt + (size_t)bh * NN * HDIM;
  const unsigned short* vgb = vg + (size_t)bh * 64 * 2048;

  const bf16x8_t qf0 = *(const bf16x8_t*)(qb + ((size_t)g * NN + nbase + l16) * 8);
  const bf16x8_t qf1 = *(const bf16x8_t*)(qb + ((size_t)g * NN + nbase + 16 + l16) * 8);

  f32x4_t o00 = {0, 0, 0, 0}, o01 = {0, 0, 0, 0};  // t0: d=g*4+r, d+16
  f32x4_t o10 = {0, 0, 0, 0}, o11 = {0, 0, 0, 0};  // t1
  f32x4_t la = {0, 0, 0, 0}, lb = {0, 0, 0, 0};    // l sums via ones-MFMA
  const f32x4_t zf = {0, 0, 0, 0};
  const i32x4_t onesi = {0x3F803F80, 0x3F803F80, 0x3F803F80, 0x3F803F80};
  const bf16x8_t ones = __builtin_bit_cast(bf16x8_t, onesi);

  const int NITER = 64 / KSPLIT;  // 32
  const int mt0 = chunk * NITER;

  const unsigned short* ksrc = kb + ((size_t)g * NN + mt0 * 64 + wid * 16 + l16) * 8;
  const unsigned short* vsrc = vgb + (size_t)mt0 * 2048 + (size_t)((wid * 16 + l16) * 4 + g) * 8;

  auto stage = [&](int p, int i) {
    gload_lds16(ksrc + (size_t)i * 512, &smem[p][wid * 512]);
    gload_lds16(vsrc + (size_t)i * 2048, &smem[p][2048 + wid * 512]);
  };

  f32x4_t Sx[8], Sy[8];

  // QK^T for one tile: 4 K ds_reads + 8 MFMA into S[0..7]
  auto qk = [&](int p, f32x4_t (&S)[8]) {
    const unsigned short* sk = &smem[p][0];
    bf16x8_t k0 = *(const bf16x8_t*)(sk + 0 * 512 + lane * 8);
    bf16x8_t k1 = *(const bf16x8_t*)(sk + 1 * 512 + lane * 8);
    bf16x8_t k2 = *(const bf16x8_t*)(sk + 2 * 512 + lane * 8);
    bf16x8_t k3 = *(const bf16x8_t*)(sk + 3 * 512 + lane * 8);
    __builtin_amdgcn_s_setprio(1);
    S[0] = MFMA16(k0, qf0, zf); S[1] = MFMA16(k1, qf0, zf);
    S[2] = MFMA16(k2, qf0, zf); S[3] = MFMA16(k3, qf0, zf);
    S[4] = MFMA16(k0, qf1, zf); S[5] = MFMA16(k1, qf1, zf);
    S[6] = MFMA16(k2, qf1, zf); S[7] = MFMA16(k3, qf1, zf);
    __builtin_amdgcn_s_setprio(0);
  };

  // exp2 + pack + PV + l for one tile; V read from LDS (buffer safe: its
  // next overwrite is >=2 barriers away).
  auto rest = [&](int p, f32x4_t (&S)[8]) {
    const unsigned short* sv = &smem[p][2048];
    bf16x8_t vf0 = *(const bf16x8_t*)(sv + 0 * 512 + lane * 8);  // f0,h0
    bf16x8_t vf2 = *(const bf16x8_t*)(sv + 1 * 512 + lane * 8);  // f0,h1
    bf16x8_t vf1 = *(const bf16x8_t*)(sv + 2 * 512 + lane * 8);  // f1,h0
    bf16x8_t vf3 = *(const bf16x8_t*)(sv + 3 * 512 + lane * 8);  // f1,h1

#pragma unroll
    for (int j = 0; j < 8; j++) {
#pragma unroll
      for (int r = 0; r < 4; r++) S[j][r] = EXP2(S[j][r]);
    }

    i32x4_t pA0i = {(int)pack_trunc(S[0][0], S[0][1]), (int)pack_trunc(S[0][2], S[0][3]),
                    (int)pack_trunc(S[1][0], S[1][1]), (int)pack_trunc(S[1][2], S[1][3])};
    i32x4_t pA1i = {(int)pack_trunc(S[2][0], S[2][1]), (int)pack_trunc(S[2][2], S[2][3]),
                    (int)pack_trunc(S[3][0], S[3][1]), (int)pack_trunc(S[3][2], S[3][3])};
    i32x4_t pB0i = {(int)pack_trunc(S[4][0], S[4][1]), (int)pack_trunc(S[4][2], S[4][3]),
                    (int)pack_trunc(S[5][0], S[5][1]), (int)pack_trunc(S[5][2], S[5][3])};
    i32x4_t pB1i = {(int)pack_trunc(S[6][0], S[6][1]), (int)pack_trunc(S[6][2], S[6][3]),
                    (int)pack_trunc(S[7][0], S[7][1]), (int)pack_trunc(S[7][2], S[7][3])};
    bf16x8_t pA0 = __builtin_bit_cast(bf16x8_t, pA0i);
    bf16x8_t pA1 = __builtin_bit_cast(bf16x8_t, pA1i);
    bf16x8_t pB0 = __builtin_bit_cast(bf16x8_t, pB0i);
    bf16x8_t pB1 = __builtin_bit_cast(bf16x8_t, pB1i);

    __builtin_amdgcn_s_setprio(1);
    o00 = MFMA16(vf0, pA0, o00); o00 = MFMA16(vf1, pA1, o00);
    o01 = MFMA16(vf2, pA0, o01); o01 = MFMA16(vf3, pA1, o01);
    o10 = MFMA16(vf0, pB0, o10); o10 = MFMA16(vf1, pB1, o10);
    o11 = MFMA16(vf2, pB0, o11); o11 = MFMA16(vf3, pB1, o11);

    la = MFMA16(ones, pA0, la); la = MFMA16(ones, pA1, la);
    lb = MFMA16(ones, pB0, lb); lb = MFMA16(ones, pB1, lb);
    __builtin_amdgcn_s_setprio(0);
  };

  // prologue: tiles 0,1 staged; scores for tile 0
  stage(0, 0);
  stage(1, 1);
  __syncthreads();
  qk(0, Sx);

  for (int mi = 0; mi < NITER - 2; mi += 2) {
    stage((mi + 2) & 3, mi + 2);
    qk((mi + 1) & 3, Sy);       // tile mi+1 (independent of rest below)
    rest(mi & 3, Sx);           // tile mi
    __syncthreads();
    if (mi + 3 < NITER) stage((mi + 3) & 3, mi + 3);
    qk((mi + 2) & 3, Sx);       // tile mi+2
    rest((mi + 1) & 3, Sy);     // tile mi+1
    __syncthreads();
  }
  // epilogue: tiles NITER-2 (scores in Sx), NITER-1 (staged, not yet QK'd)
  qk((NITER - 1) & 3, Sy);
  rest((NITER - 2) & 3, Sx);
  rest((NITER - 1) & 3, Sy);

  // write unnormalized partials, bf16-packed: opart[chunk][bh][cd] rows of
  // NN/2 dwords; dword (wnd*16 + j) holds (n = wnd*32+j, n = wnd*32+16+j).
  // Each quarter (16 lanes) stores 64 contiguous aligned bytes.
  unsigned* ob32 = opart + ((size_t)(chunk * BB * NHEAD + bh)) * HDIM * (NN / 2);
  const int wnd16 = (nbase >> 5) * 16;  // dword base of this wave's window
#pragma unroll
  for (int r = 0; r < 4; r++) {
    ob32[(size_t)(g * 4 + r) * (NN / 2) + wnd16 + l16] = pk2(o00[r], o10[r]);
    ob32[(size_t)(16 + g * 4 + r) * (NN / 2) + wnd16 + l16] = pk2(o01[r], o11[r]);
  }
  if (g == 0) {
    float* lb_ = lpart + (size_t)(chunk * BB * NHEAD + bh) * NN;
    lb_[nbase + l16] = la[0];
    lb_[nbase + 16 + l16] = lb[0];
  }
}

// ---------------------------------------------------------------------------
// Output projection fused with partial-combine — unchanged from r8/r14.
// Reads bf16-packed opart + lpart, sums KSPLIT chunks, normalizes, packs
// bf16 into xsb [n][c]; wo fp32->bf16 into wsb; MFMA + bias + residual,
// fp32 out. Grid (64 ntiles, B), 512 thr.
// ---------------------------------------------------------------------------
__global__ __launch_bounds__(512) void out_mfma_kernel(
    const unsigned* __restrict__ opart, const float* __restrict__ lpart,
    const float* __restrict__ wo, const float* __restrict__ bo,
    const float* __restrict__ x, float* __restrict__ out) {
  __shared__ __attribute__((aligned(16))) unsigned short wsb[128][136];  // 34.8KB
  __shared__ __attribute__((aligned(16))) unsigned short xsb[64][136];   // 17.4KB
  __shared__ float linv[NHEAD][64];
  const int b = blockIdx.y, nt = blockIdx.x;
  const int tid = threadIdx.x;

  // stage wo -> bf16 LDS: 4096 float4 over 512 thr, packed b64 LDS writes
#pragma unroll
  for (int i = 0; i < 8; i++) {
    int idx = i * 512 + tid;
    int o = idx >> 5, c4 = (idx & 31) * 4;
    float4 v4 = *(const float4*)(wo + (size_t)o * CC + c4);
    uint2 p;
    p.x = pk2(v4.x, v4.y);
    p.y = pk2(v4.z, v4.w);
    *(uint2*)&wsb[o][c4] = p;
  }

  if (tid < 256) {  // 1/l per (h, n)
    int h = tid >> 6, nn = tid & 63;
    int bh = b * NHEAD + h;
    float l = 0.f;
#pragma unroll
    for (int c = 0; c < KSPLIT; c++)
      l += lpart[(size_t)(c * BB * NHEAD + bh) * NN + nt * 64 + nn];
    linv[h][nn] = 1.f / l;
  }
  __syncthreads();

  // combine + normalize + bf16-pack into LDS from packed opart.
  const size_t ROWD = NN / 2;
  const size_t CH32 = (size_t)BB * NHEAD * HDIM * ROWD;  // chunk stride (dwords)
  const unsigned* obb = opart + (size_t)b * NHEAD * HDIM * ROWD;
#pragma unroll
  for (int i = 0; i < 2; i++) {
    int s = i * 512 + tid;  // 1024 uint4 slots (128 cd x 8)
    int cd = s >> 3, q = s & 7;
    size_t a = (size_t)cd * ROWD + nt * 32 + q * 4;
    uint4 u0 = *(const uint4*)(obb + a);
    uint4 u1 = *(const uint4*)(obb + CH32 + a);
    int nb = (q >> 2) * 32 + (q & 3) * 4;  // local n base (lo half)
    const float* li = &linv[cd >> 5][0];
    const unsigned* w0 = (const unsigned*)&u0;
    const unsigned* w1 = (const unsigned*)&u1;
#pragma unroll
    for (int e = 0; e < 4; e++) {
      float lo = __builtin_bit_cast(float, w0[e] << 16) +
                 __builtin_bit_cast(float, w1[e] << 16);
      float hi = __builtin_bit_cast(float, w0[e] & 0xFFFF0000u) +
                 __builtin_bit_cast(float, w1[e] & 0xFFFF0000u);
      int nl = nb + e;
      xsb[nl][cd] = f2bf(lo * li[nl]);
      xsb[nl + 16][cd] = f2bf(hi * li[nl + 16]);
    }
  }
  __syncthreads();

  const int lane = tid & 63, w = tid >> 6;
  const int l16 = lane & 15, g = lane >> 4;
  const int nsub = (w & 3) * 16, mtbase = (w >> 2) * 4;
  const int n0 = nt * 64 + nsub;

  bf16x8_t bfr[4];
#pragma unroll
  for (int ks = 0; ks < 4; ks++)
    bfr[ks] = *(const bf16x8_t*)&xsb[nsub + l16][ks * 32 + g * 8];

#pragma unroll
  for (int mi = 0; mi < 4; mi++) {
    int mt = mtbase + mi;
    f32x4_t acc;
#pragma unroll
    for (int r = 0; r < 4; r++) acc[r] = bo[mt * 16 + g * 4 + r];
#pragma unroll
    for (int ks = 0; ks < 4; ks++) {
      bf16x8_t af = *(const bf16x8_t*)&wsb[mt * 16 + l16][ks * 32 + g * 8];
      acc = MFMA16(af, bfr[ks], acc);
    }
#pragma unroll
    for (int r = 0; r < 4; r++) {
      int o = mt * 16 + g * 4 + r;
      size_t addr = ((size_t)b * CC + o) * NN + n0 + l16;
      out[addr] = acc[r] + x[addr];
    }
  }
}

extern "C" void kernel_launch(void* const* d_in, const int* in_sizes, int n_in,
                              void* d_out, int out_size, void* d_ws, size_t ws_size,
                              hipStream_t stream) {
  const float* x  = (const float*)d_in[0];
  const float* wq = (const float*)d_in[1];
  const float* bq = (const float*)d_in[2];
  const float* wk = (const float*)d_in[3];
  const float* bk = (const float*)d_in[4];
  const float* wv = (const float*)d_in[5];
  const float* bv = (const float*)d_in[6];
  const float* wo = (const float*)d_in[7];
  const float* bo = (const float*)d_in[8];
  float* out = (float*)d_out;

  char* w = (char*)d_ws;
  const size_t SZ = (size_t)BB * NHEAD * NN * HDIM * 2;  // 4 MB (bf16 buffer bytes)
  unsigned short* qt    = (unsigned short*)w;            // 4 MB
  unsigned short* kt    = (unsigned short*)(w + SZ);     // 4 MB
  unsigned short* vg    = (unsigned short*)(w + 2 * SZ); // 4 MB (gathered V)
  unsigned* opart = (unsigned*)(w + 3 * SZ);             // KSPLIT * 4 MB (bf16 packed)
  float* lpart = (float*)(w + 3 * SZ +
                          (size_t)KSPLIT * BB * NHEAD * HDIM * NN * 2);  // KSPLIT * 256 KB

  qkv_mfma_kernel<<<dim3(NN / 64, BB, 3), 256, 0, stream>>>(
      x, wq, wk, wv, bq, bk, bv, qt, kt, vg);
  attn_mfma5_kernel<<<dim3((NN / 128) * KSPLIT, NHEAD, BB), 256, 0, stream>>>(
      qt, kt, vg, opart, lpart);
  out_mfma_kernel<<<dim3(NN / 64, BB), 512, 0, stream>>>(
      opart, lpart, wo, bo, x, out);
}

// Round 16
// 129.878 us; speedup vs baseline: 1.0103x; 1.0103x over previous
//
#include <hip/hip_runtime.h>
#include <hip/hip_bf16.h>

#define BB 4
#define CC 128
#define NN 4096
#define NHEAD 4
#define HDIM 32
#define KSPLIT 2   // FINAL: r8/r14 config (best verified: 128.2-129.1us).
// Complete session ledger (15 rounds):
// - attn is ISSUE-BOUND (MfmaUtil 36 + VALUBusy 51) under this structure.
//   Null levers, each counter-verified: occupancy (r13: 8 waves/SIMD, dur
//   unchanged), BW/L2 locality (r11: FETCH -3.3x, dur unchanged), KSPLIT=4
//   (r13), intra-wave 2-tile pipeline (r15: compiler serializes qk/rest,
//   VGPR 72, dur +2us).
// - r2/r10/r12 "explosions" (FETCH 440MB) were REGISTER SPILLS from
//   __launch_bounds__(256,8) forcing VGPR 56->32. Never strangle the
//   allocator; VGPR_Count in counters is the tell.
// - r6: W fragments must come from LDS inside the MFMA loop (+8.7us if not).
// - r7: qkv@512thr (wave ot-split) raced graph-replay verification.
// - r9: staging-VALU micro-opts regressed (qkv/out are latency-bound).
// - Pipeline fusion r0->r8 (combine kernel eliminated, prep fused into
//   qkv/out, bf16 full-line packed partials): 148.4 -> 128.2us.
// Remaining paths (not taken): 32x32-MFMA attn restructure or persistent
// fused kernel — multi-round, r7-class race risk, no counter evidence of
// >5% headroom.

typedef short bf16x8_t __attribute__((ext_vector_type(8)));  // 8 bf16 (4 VGPRs)
typedef float f32x4_t __attribute__((ext_vector_type(4)));
typedef int i32x4_t __attribute__((ext_vector_type(4)));

#define MFMA16(a, b, c) __builtin_amdgcn_mfma_f32_16x16x32_bf16(a, b, c, 0, 0, 0)
#define EXP2(x) __builtin_amdgcn_exp2f(x)

// scores use exp2: fold log2(e) into q scale (softmax invariant)
#define QSCALE (0.17677669529663687f * 1.4426950408889634f)

// RNE float->bf16 (finite inputs only)
static __device__ inline unsigned short f2bf(float f) {
  unsigned u = __builtin_bit_cast(unsigned, f);
  u += 0x7fffu + ((u >> 16) & 1u);
  return (unsigned short)(u >> 16);
}
static __device__ inline unsigned pk2(float lo, float hi) {  // RNE pack pair
  return (unsigned)f2bf(lo) | ((unsigned)f2bf(hi) << 16);
}
// pack two f32 -> bf16 pair by TRUNCATION: single v_perm_b32
static __device__ inline unsigned pack_trunc(float lo, float hi) {
  return __builtin_amdgcn_perm(__builtin_bit_cast(unsigned, hi),
                               __builtin_bit_cast(unsigned, lo), 0x07060302u);
}

// async global->LDS, 16 B per lane. gsrc is PER-LANE (gather); LDS dest =
// uniform base + lane*16.
static __device__ inline void gload_lds16(const unsigned short* gsrc, void* ldst) {
  __builtin_amdgcn_global_load_lds(
      (const __attribute__((address_space(1))) unsigned int*)gsrc,
      (__attribute__((address_space(3))) unsigned int*)ldst, 16, 0, 0);
}

// ---------------------------------------------------------------------------
// QKV projection via MFMA — 256 thr, 4 waves, grid (64, B, 3).
// x-tile HBM loads issued FIRST, then W fp32->bf16 into wsb (packed uint2
// stores). vt (V transpose, proj==2 only) aliases xsb (dead after xf loads;
// barrier-2 separates).
// Epilogues:
//   Q/K: pack 4 d into 2 dwords, shfl_xor(16) pair-exchange, even-g lanes
//        store one uint4 -> layout [b][h][dblk=d/8][n][8d] bf16.
//   V:   block LDS transpose [o][n] -> vg gathered tiles, sequential uint4.
// LDS ~52.2KB -> 3 blocks/CU (768 blocks all resident).
// ---------------------------------------------------------------------------
__global__ __launch_bounds__(256) void qkv_mfma_kernel(
    const float* __restrict__ x,
    const float* __restrict__ wq, const float* __restrict__ wk,
    const float* __restrict__ wv,
    const float* __restrict__ bq, const float* __restrict__ bk,
    const float* __restrict__ bv,
    unsigned short* __restrict__ qt, unsigned short* __restrict__ kt,
    unsigned short* __restrict__ vg) {
  __shared__ __attribute__((aligned(16))) unsigned short wsb[128][136];  // 34.8KB
  __shared__ __attribute__((aligned(16))) unsigned short xsb[64][136];   // 17.4KB
  unsigned short(*vt)[66] = (unsigned short(*)[66]) & xsb[0][0];  // alias (16.9KB)

  const int b = blockIdx.y, nt = blockIdx.x, proj = blockIdx.z;
  const int tid = threadIdx.x;

  const float* wsrc = (proj == 0) ? wq : (proj == 1) ? wk : wv;
  const float wscale = (proj == 0) ? QSCALE : 1.0f;

  // stage x-tile first (HBM): [n][c] bf16 transpose
#pragma unroll
  for (int i = 0; i < 8; i++) {
    int f = tid + 256 * i;  // 2048 float4 slots
    int c = f >> 4, n4 = (f & 15) * 4;
    float4 v4 = *(const float4*)(x + ((size_t)b * CC + c) * NN + nt * 64 + n4);
    xsb[n4 + 0][c] = f2bf(v4.x);
    xsb[n4 + 1][c] = f2bf(v4.y);
    xsb[n4 + 2][c] = f2bf(v4.z);
    xsb[n4 + 3][c] = f2bf(v4.w);
  }

  // stage W: 4096 float4 over 256 thr, coalesced reads, packed b64 LDS writes
#pragma unroll
  for (int i = 0; i < 16; i++) {
    int idx = i * 256 + tid;           // float4 index
    int o = idx >> 5, c4 = (idx & 31) * 4;
    float4 v4 = *(const float4*)(wsrc + (size_t)o * CC + c4);
    uint2 p;
    p.x = pk2(v4.x * wscale, v4.y * wscale);
    p.y = pk2(v4.z * wscale, v4.w * wscale);
    *(uint2*)&wsb[o][c4] = p;  // 8B aligned: 136*2 % 8 == 0, c4*2 % 8 == 0
  }
  __syncthreads();

  const int lane = tid & 63, w = tid >> 6;
  const int l16 = lane & 15, g = lane >> 4;
  const int nl = w * 16;
  const int ngl = nt * 64 + nl;

  bf16x8_t xf[4];
#pragma unroll
  for (int ks = 0; ks < 4; ks++)
    xf[ks] = *(const bf16x8_t*)&xsb[nl + l16][ks * 32 + g * 8];
  __syncthreads();  // xsb dead; vt (alias) may now be written

  const float* bias = (proj == 0) ? bq : (proj == 1) ? bk : bv;
  const float bsc = (proj == 0) ? QSCALE : 1.0f;
  unsigned short* qkdst = proj ? kt : qt;

#pragma unroll
  for (int ot = 0; ot < 8; ot++) {
    f32x4_t acc;
#pragma unroll
    for (int r = 0; r < 4; r++) acc[r] = bias[ot * 16 + g * 4 + r] * bsc;
#pragma unroll
    for (int ks = 0; ks < 4; ks++) {
      bf16x8_t wf = *(const bf16x8_t*)&wsb[ot * 16 + l16][ks * 32 + g * 8];
      acc = MFMA16(wf, xf[ks], acc);
    }
    if (proj < 2) {
      // lane holds d = (ot&15 base) consecutive 4; pair with g^1 for 8
      unsigned p0 = pk2(acc[0], acc[1]);
      unsigned p1 = pk2(acc[2], acc[3]);
      unsigned q0 = (unsigned)__shfl_xor((int)p0, 16);
      unsigned q1 = (unsigned)__shfl_xor((int)p1, 16);
      if ((g & 1) == 0) {
        int hh = ot >> 1, dblk = (ot & 1) * 2 + (g >> 1);
        unsigned short* dst =
            qkdst + (((size_t)(b * NHEAD + hh) * 4 + dblk) * NN + ngl + l16) * 8;
        uint4 val = make_uint4(p0, p1, q0, q1);
        *(uint4*)dst = val;
      }
    } else {
#pragma unroll
      for (int r = 0; r < 4; r++) vt[ot * 16 + g * 4 + r][nl + l16] = f2bf(acc[r]);
    }
  }

  if (proj == 2) {
    __syncthreads();
    // emit vg: 1024 16B chunks, perfectly sequential stores
#pragma unroll
    for (int c = 0; c < 4; c++) {
      int cid = c * 256 + tid;
      int hh = cid >> 8, inner = cid & 255;
      int g2 = inner & 3, l16v = (inner >> 2) & 15, fh = inner >> 6;
      int fv = fh >> 1, half = fh & 1;
      int o = hh * 32 + half * 16 + l16v;
      int n0 = fv * 32 + g2 * 4;
      unsigned d0 = *(const unsigned*)&vt[o][n0];
      unsigned d1 = *(const unsigned*)&vt[o][n0 + 2];
      unsigned d2 = *(const unsigned*)&vt[o][n0 + 16];
      unsigned d3 = *(const unsigned*)&vt[o][n0 + 18];
      uint4 val = make_uint4(d0, d1, d2, d3);
      *(uint4*)(vg + (((size_t)(b * NHEAD + hh) * 64 + nt) * 256 + inner) * 8) = val;
    }
  }
}

// ---------------------------------------------------------------------------
// Flash attention, bf16 MFMA — r8 configuration (best verified): KSPLIT=2,
// launch_bounds(256,4) (VGPR=56, no spill), setprio around MFMA clusters,
// bf16-packed opart with full-line store geometry, natural block order.
// ---------------------------------------------------------------------------
__global__ __launch_bounds__(256, 4) void attn_mfma5_kernel(
    const unsigned short* __restrict__ qt, const unsigned short* __restrict__ kt,
    const unsigned short* __restrict__ vg,
    unsigned* __restrict__ opart, float* __restrict__ lpart) {
  __shared__ __attribute__((aligned(16))) unsigned short smem[2][4096];  // [buf]: K 2048, V 2048

  const int chunk = blockIdx.x & (KSPLIT - 1), nt = blockIdx.x / KSPLIT;
  const int h = blockIdx.y, b = blockIdx.z;
  const int bh = b * NHEAD + h;
  const int tid = threadIdx.x, lane = tid & 63, wid = tid >> 6;
  const int l16 = lane & 15, g = lane >> 4;
  const int nbase = nt * 128 + wid * 32;

  const unsigned short* qb = qt + (size_t)bh * NN * HDIM;  // [dblk][n][8]
  const unsigned short* kb = kt + (size_t)bh * NN * HDIM;
  const unsigned short* vgb = vg + (size_t)bh * 64 * 2048;

  const bf16x8_t qf0 = *(const bf16x8_t*)(qb + ((size_t)g * NN + nbase + l16) * 8);
  const bf16x8_t qf1 = *(const bf16x8_t*)(qb + ((size_t)g * NN + nbase + 16 + l16) * 8);

  f32x4_t o00 = {0, 0, 0, 0}, o01 = {0, 0, 0, 0};  // t0: d=g*4+r, d+16
  f32x4_t o10 = {0, 0, 0, 0}, o11 = {0, 0, 0, 0};  // t1
  f32x4_t la = {0, 0, 0, 0}, lb = {0, 0, 0, 0};    // l sums via ones-MFMA
  const f32x4_t zf = {0, 0, 0, 0};
  const i32x4_t onesi = {0x3F803F80, 0x3F803F80, 0x3F803F80, 0x3F803F80};
  const bf16x8_t ones = __builtin_bit_cast(bf16x8_t, onesi);

  const int NITER = 64 / KSPLIT;
  const int mt0 = chunk * NITER;

  const unsigned short* ksrc = kb + ((size_t)g * NN + mt0 * 64 + wid * 16 + l16) * 8;
  const unsigned short* vsrc = vgb + (size_t)mt0 * 2048 + (size_t)((wid * 16 + l16) * 4 + g) * 8;

  auto stage = [&](int p, int i) {
    gload_lds16(ksrc + (size_t)i * 512, &smem[p][wid * 512]);
    gload_lds16(vsrc + (size_t)i * 2048, &smem[p][2048 + wid * 512]);
  };

  auto body = [&](int p) {
    const unsigned short* sk = &smem[p][0];
    bf16x8_t k0 = *(const bf16x8_t*)(sk + 0 * 512 + lane * 8);
    bf16x8_t k1 = *(const bf16x8_t*)(sk + 1 * 512 + lane * 8);
    bf16x8_t k2 = *(const bf16x8_t*)(sk + 2 * 512 + lane * 8);
    bf16x8_t k3 = *(const bf16x8_t*)(sk + 3 * 512 + lane * 8);
    bf16x8_t vf0 = *(const bf16x8_t*)(sk + 2048 + 0 * 512 + lane * 8);  // f0,h0
    bf16x8_t vf2 = *(const bf16x8_t*)(sk + 2048 + 1 * 512 + lane * 8);  // f0,h1
    bf16x8_t vf1 = *(const bf16x8_t*)(sk + 2048 + 2 * 512 + lane * 8);  // f1,h0
    bf16x8_t vf3 = *(const bf16x8_t*)(sk + 2048 + 3 * 512 + lane * 8);  // f1,h1

    __builtin_amdgcn_s_setprio(1);
    f32x4_t sA0 = MFMA16(k0, qf0, zf), sA1 = MFMA16(k1, qf0, zf);
    f32x4_t sA2 = MFMA16(k2, qf0, zf), sA3 = MFMA16(k3, qf0, zf);
    f32x4_t sB0 = MFMA16(k0, qf1, zf), sB1 = MFMA16(k1, qf1, zf);
    f32x4_t sB2 = MFMA16(k2, qf1, zf), sB3 = MFMA16(k3, qf1, zf);
    __builtin_amdgcn_s_setprio(0);

#pragma unroll
    for (int r = 0; r < 4; r++) {
      sA0[r] = EXP2(sA0[r]); sA1[r] = EXP2(sA1[r]);
      sA2[r] = EXP2(sA2[r]); sA3[r] = EXP2(sA3[r]);
      sB0[r] = EXP2(sB0[r]); sB1[r] = EXP2(sB1[r]);
      sB2[r] = EXP2(sB2[r]); sB3[r] = EXP2(sB3[r]);
    }

    i32x4_t pA0i = {(int)pack_trunc(sA0[0], sA0[1]), (int)pack_trunc(sA0[2], sA0[3]),
                    (int)pack_trunc(sA1[0], sA1[1]), (int)pack_trunc(sA1[2], sA1[3])};
    i32x4_t pA1i = {(int)pack_trunc(sA2[0], sA2[1]), (int)pack_trunc(sA2[2], sA2[3]),
                    (int)pack_trunc(sA3[0], sA3[1]), (int)pack_trunc(sA3[2], sA3[3])};
    i32x4_t pB0i = {(int)pack_trunc(sB0[0], sB0[1]), (int)pack_trunc(sB0[2], sB0[3]),
                    (int)pack_trunc(sB1[0], sB1[1]), (int)pack_trunc(sB1[2], sB1[3])};
    i32x4_t pB1i = {(int)pack_trunc(sB2[0], sB2[1]), (int)pack_trunc(sB2[2], sB2[3]),
                    (int)pack_trunc(sB3[0], sB3[1]), (int)pack_trunc(sB3[2], sB3[3])};
    bf16x8_t pA0 = __builtin_bit_cast(bf16x8_t, pA0i);
    bf16x8_t pA1 = __builtin_bit_cast(bf16x8_t, pA1i);
    bf16x8_t pB0 = __builtin_bit_cast(bf16x8_t, pB0i);
    bf16x8_t pB1 = __builtin_bit_cast(bf16x8_t, pB1i);

    __builtin_amdgcn_s_setprio(1);
    o00 = MFMA16(vf0, pA0, o00); o00 = MFMA16(vf1, pA1, o00);
    o01 = MFMA16(vf2, pA0, o01); o01 = MFMA16(vf3, pA1, o01);
    o10 = MFMA16(vf0, pB0, o10); o10 = MFMA16(vf1, pB1, o10);
    o11 = MFMA16(vf2, pB0, o11); o11 = MFMA16(vf3, pB1, o11);

    la = MFMA16(ones, pA0, la); la = MFMA16(ones, pA1, la);
    lb = MFMA16(ones, pB0, lb); lb = MFMA16(ones, pB1, lb);
    __builtin_amdgcn_s_setprio(0);
  };

  stage(0, 0);
  __syncthreads();
  for (int mi = 0; mi < NITER; mi += 2) {
    stage(1, mi + 1);
    body(0);
    __syncthreads();
    if (mi + 2 < NITER) stage(0, mi + 2);
    body(1);
    __syncthreads();
  }

  // write unnormalized partials, bf16-packed: opart[chunk][bh][cd] rows of
  // NN/2 dwords; dword (wnd*16 + j) holds (n = wnd*32+j, n = wnd*32+16+j).
  // Each quarter (16 lanes) stores 64 contiguous aligned bytes.
  unsigned* ob32 = opart + ((size_t)(chunk * BB * NHEAD + bh)) * HDIM * (NN / 2);
  const int wnd16 = (nbase >> 5) * 16;  // dword base of this wave's window
#pragma unroll
  for (int r = 0; r < 4; r++) {
    ob32[(size_t)(g * 4 + r) * (NN / 2) + wnd16 + l16] = pk2(o00[r], o10[r]);
    ob32[(size_t)(16 + g * 4 + r) * (NN / 2) + wnd16 + l16] = pk2(o01[r], o11[r]);
  }
  if (g == 0) {
    float* lb_ = lpart + (size_t)(chunk * BB * NHEAD + bh) * NN;
    lb_[nbase + l16] = la[0];
    lb_[nbase + 16 + l16] = lb[0];
  }
}

// ---------------------------------------------------------------------------
// Output projection fused with partial-combine — reads bf16-packed opart +
// lpart, sums KSPLIT chunks, normalizes, packs bf16 into xsb [n][c]; wo
// fp32->bf16 into wsb (packed b64 stores); MFMA + bias + residual, fp32
// out. Grid (64 ntiles, B), 512 thr: 8 waves = (4 n-subtiles) x (2 mt-halves).
// ---------------------------------------------------------------------------
__global__ __launch_bounds__(512) void out_mfma_kernel(
    const unsigned* __restrict__ opart, const float* __restrict__ lpart,
    const float* __restrict__ wo, const float* __restrict__ bo,
    const float* __restrict__ x, float* __restrict__ out) {
  __shared__ __attribute__((aligned(16))) unsigned short wsb[128][136];  // 34.8KB
  __shared__ __attribute__((aligned(16))) unsigned short xsb[64][136];   // 17.4KB
  __shared__ float linv[NHEAD][64];
  const int b = blockIdx.y, nt = blockIdx.x;
  const int tid = threadIdx.x;

  // stage wo -> bf16 LDS: 4096 float4 over 512 thr, packed b64 LDS writes
#pragma unroll
  for (int i = 0; i < 8; i++) {
    int idx = i * 512 + tid;
    int o = idx >> 5, c4 = (idx & 31) * 4;
    float4 v4 = *(const float4*)(wo + (size_t)o * CC + c4);
    uint2 p;
    p.x = pk2(v4.x, v4.y);
    p.y = pk2(v4.z, v4.w);
    *(uint2*)&wsb[o][c4] = p;
  }

  if (tid < 256) {  // 1/l per (h, n)
    int h = tid >> 6, nn = tid & 63;
    int bh = b * NHEAD + h;
    float l = 0.f;
#pragma unroll
    for (int c = 0; c < KSPLIT; c++)
      l += lpart[(size_t)(c * BB * NHEAD + bh) * NN + nt * 64 + nn];
    linv[h][nn] = 1.f / l;
  }
  __syncthreads();

  // combine + normalize + bf16-pack into LDS from packed opart.
  // Row cd has NN/2 dwords; tile covers dwords [nt*32, nt*32+32) = 8 uint4.
  // uint4 slot q (0..7): local window (q>>2), j = (q&3)*4; dword e holds
  // (n_lo = (q>>2)*32 + j + e, n_hi = n_lo + 16).
  const size_t ROWD = NN / 2;
  const size_t CH32 = (size_t)BB * NHEAD * HDIM * ROWD;  // chunk stride (dwords)
  const unsigned* obb = opart + (size_t)b * NHEAD * HDIM * ROWD;
#pragma unroll
  for (int i = 0; i < 2; i++) {
    int s = i * 512 + tid;  // 1024 uint4 slots (128 cd x 8)
    int cd = s >> 3, q = s & 7;
    size_t a = (size_t)cd * ROWD + nt * 32 + q * 4;
    uint4 u0 = *(const uint4*)(obb + a);
    uint4 u1 = *(const uint4*)(obb + CH32 + a);
    int nb = (q >> 2) * 32 + (q & 3) * 4;  // local n base (lo half)
    const float* li = &linv[cd >> 5][0];
    const unsigned* w0 = (const unsigned*)&u0;
    const unsigned* w1 = (const unsigned*)&u1;
#pragma unroll
    for (int e = 0; e < 4; e++) {
      float lo = __builtin_bit_cast(float, w0[e] << 16) +
                 __builtin_bit_cast(float, w1[e] << 16);
      float hi = __builtin_bit_cast(float, w0[e] & 0xFFFF0000u) +
                 __builtin_bit_cast(float, w1[e] & 0xFFFF0000u);
      int nl = nb + e;
      xsb[nl][cd] = f2bf(lo * li[nl]);
      xsb[nl + 16][cd] = f2bf(hi * li[nl + 16]);
    }
  }
  __syncthreads();

  const int lane = tid & 63, w = tid >> 6;
  const int l16 = lane & 15, g = lane >> 4;
  const int nsub = (w & 3) * 16, mtbase = (w >> 2) * 4;
  const int n0 = nt * 64 + nsub;

  bf16x8_t bfr[4];
#pragma unroll
  for (int ks = 0; ks < 4; ks++)
    bfr[ks] = *(const bf16x8_t*)&xsb[nsub + l16][ks * 32 + g * 8];

#pragma unroll
  for (int mi = 0; mi < 4; mi++) {
    int mt = mtbase + mi;
    f32x4_t acc;
#pragma unroll
    for (int r = 0; r < 4; r++) acc[r] = bo[mt * 16 + g * 4 + r];
#pragma unroll
    for (int ks = 0; ks < 4; ks++) {
      bf16x8_t af = *(const bf16x8_t*)&wsb[mt * 16 + l16][ks * 32 + g * 8];
      acc = MFMA16(af, bfr[ks], acc);
    }
#pragma unroll
    for (int r = 0; r < 4; r++) {
      int o = mt * 16 + g * 4 + r;
      size_t addr = ((size_t)b * CC + o) * NN + n0 + l16;
      out[addr] = acc[r] + x[addr];
    }
  }
}

extern "C" void kernel_launch(void* const* d_in, const int* in_sizes, int n_in,
                              void* d_out, int out_size, void* d_ws, size_t ws_size,
                              hipStream_t stream) {
  const float* x  = (const float*)d_in[0];
  const float* wq = (const float*)d_in[1];
  const float* bq = (const float*)d_in[2];
  const float* wk = (const float*)d_in[3];
  const float* bk = (const float*)d_in[4];
  const float* wv = (const float*)d_in[5];
  const float* bv = (const float*)d_in[6];
  const float* wo = (const float*)d_in[7];
  const float* bo = (const float*)d_in[8];
  float* out = (float*)d_out;

  char* w = (char*)d_ws;
  const size_t SZ = (size_t)BB * NHEAD * NN * HDIM * 2;  // 4 MB (bf16 buffer bytes)
  unsigned short* qt    = (unsigned short*)w;            // 4 MB
  unsigned short* kt    = (unsigned short*)(w + SZ);     // 4 MB
  unsigned short* vg    = (unsigned short*)(w + 2 * SZ); // 4 MB (gathered V)
  unsigned* opart = (unsigned*)(w + 3 * SZ);             // KSPLIT * 4 MB (bf16 packed)
  float* lpart = (float*)(w + 3 * SZ +
                          (size_t)KSPLIT * BB * NHEAD * HDIM * NN * 2);  // KSPLIT * 256 KB

  qkv_mfma_kernel<<<dim3(NN / 64, BB, 3), 256, 0, stream>>>(
      x, wq, wk, wv, bq, bk, bv, qt, kt, vg);
  attn_mfma5_kernel<<<dim3((NN / 128) * KSPLIT, NHEAD, BB), 256, 0, stream>>>(
      qt, kt, vg, opart, lpart);
  out_mfma_kernel<<<dim3(NN / 64, BB), 512, 0, stream>>>(
      opart, lpart, wo, bo, x, out);
}